// Round 1
// baseline (164.485 us; speedup 1.0000x reference)
//
#include <hip/hip_runtime.h>
#include <stdint.h>

#define B_ 2
#define C_ 256
#define G_ 32
#define N_ 4096
#define EPS_ 1e-5f
#define SCALE_ 0.0625f

typedef short short8 __attribute__((ext_vector_type(8)));
typedef float f32x4 __attribute__((ext_vector_type(4)));

static __device__ __forceinline__ unsigned short f2bf(float f) {
    union { float f; unsigned int u; } v; v.f = f;
    unsigned int r = v.u + 0x7FFF + ((v.u >> 16) & 1);
    return (unsigned short)(r >> 16);
}

// ---------------- GroupNorm stats: one block per (b,g), contiguous 32768 floats
__global__ void gn_stats(const float* __restrict__ x, float2* __restrict__ stats) {
    const float4* p = reinterpret_cast<const float4*>(x + (size_t)blockIdx.x * 32768);
    float s = 0.f, ss = 0.f;
    for (int i = threadIdx.x; i < 8192; i += 256) {
        float4 v = p[i];
        s  += v.x + v.y + v.z + v.w;
        ss += v.x*v.x + v.y*v.y + v.z*v.z + v.w*v.w;
    }
    for (int m = 32; m; m >>= 1) { s += __shfl_down(s, m, 64); ss += __shfl_down(ss, m, 64); }
    __shared__ float as_[4], as2_[4];
    int w = threadIdx.x >> 6;
    if ((threadIdx.x & 63) == 0) { as_[w] = s; as2_[w] = ss; }
    __syncthreads();
    if (threadIdx.x == 0) {
        float S = as_[0]+as_[1]+as_[2]+as_[3], SS = as2_[0]+as2_[1]+as2_[2]+as2_[3];
        float mu = S / 32768.f;
        float var = SS / 32768.f - mu*mu;
        stats[blockIdx.x] = make_float2(mu, rsqrtf(var + EPS_));
    }
}

// ---------------- convert 4x (256x256) f32 weights -> bf16
__global__ void wconv(const float* __restrict__ a, const float* __restrict__ b,
                      const float* __restrict__ c, const float* __restrict__ d,
                      ushort* __restrict__ o) {
    int t = blockIdx.x * 256 + threadIdx.x;
    int idx = t * 4;                       // 0..262143, never straddles a W
    const float* src = (idx >> 16) == 0 ? a : (idx >> 16) == 1 ? b : (idx >> 16) == 2 ? c : d;
    float4 v = *reinterpret_cast<const float4*>(src + (idx & 65535));
    ushort4 r; r.x = f2bf(v.x); r.y = f2bf(v.y); r.z = f2bf(v.z); r.w = f2bf(v.w);
    *reinterpret_cast<ushort4*>(o + idx) = r;
}

// ---------------- normalize + transpose: ht[b][n][c] bf16
__global__ void gnorm_t(const float* __restrict__ x, const float2* __restrict__ stats,
                        const float* __restrict__ gamma, const float* __restrict__ beta,
                        ushort* __restrict__ ht) {
    __shared__ float tile[32][33];
    int b = blockIdx.z, n0 = blockIdx.x * 32, c0 = blockIdx.y * 32;
    int tx = threadIdx.x, ty = threadIdx.y;
    #pragma unroll
    for (int i = 0; i < 4; i++) {
        int c = c0 + ty + i*8;
        float2 st = stats[b*32 + (c >> 3)];
        float v = x[((size_t)(b*C_ + c))*N_ + n0 + tx];
        tile[ty + i*8][tx] = (v - st.x) * st.y * gamma[c] + beta[c];
    }
    __syncthreads();
    #pragma unroll
    for (int i = 0; i < 4; i++) {
        int n = n0 + ty + i*8;
        ht[((size_t)(b*N_ + n))*C_ + c0 + tx] = f2bf(tile[tx][ty + i*8]);
    }
}

// ---------------- generic NT GEMM: C[i][j] = sum_k A[i][k]*B[j][k] + bias (+resid)
// K = 256 fixed. 64x64 tile, 4 waves (each 16 rows x 64 cols).
template<bool BIAS_ROW, bool RES_F32OUT>
__global__ __launch_bounds__(256) void gemm_nt(
    const ushort* __restrict__ A, const ushort* __restrict__ Bm,
    const float* __restrict__ bias, const float* __restrict__ resid,
    void* __restrict__ outp,
    long aBatch, long bBatch, long oBatch, long rBatch, int ldo)
{
    __shared__ ushort sA[64][72];
    __shared__ ushort sB[64][72];
    int bz = blockIdx.z;
    const ushort* Ab = A + (size_t)aBatch * bz;
    const ushort* Bb = Bm + (size_t)bBatch * bz;
    int i0 = blockIdx.x * 64, j0 = blockIdx.y * 64;
    int tid = threadIdx.x, w = tid >> 6, lane = tid & 63, lr = lane & 15, lg = lane >> 4;
    f32x4 acc[4] = {};
    for (int ks = 0; ks < 256; ks += 64) {
        #pragma unroll
        for (int it = 0; it < 2; it++) {
            int ch = tid + it*256;           // 0..511
            int row = ch >> 3, cc = ch & 7;
            *reinterpret_cast<uint4*>(&sA[row][cc*8]) =
                *reinterpret_cast<const uint4*>(Ab + ((size_t)(i0 + row))*256 + ks + cc*8);
            *reinterpret_cast<uint4*>(&sB[row][cc*8]) =
                *reinterpret_cast<const uint4*>(Bb + ((size_t)(j0 + row))*256 + ks + cc*8);
        }
        __syncthreads();
        #pragma unroll
        for (int kc = 0; kc < 2; kc++) {
            short8 af = *reinterpret_cast<const short8*>(&sA[w*16 + lr][kc*32 + lg*8]);
            #pragma unroll
            for (int cb = 0; cb < 4; cb++) {
                short8 bf = *reinterpret_cast<const short8*>(&sB[cb*16 + lr][kc*32 + lg*8]);
                acc[cb] = __builtin_amdgcn_mfma_f32_16x16x32_bf16(af, bf, acc[cb], 0, 0, 0);
            }
        }
        __syncthreads();
    }
    #pragma unroll
    for (int cb = 0; cb < 4; cb++) {
        #pragma unroll
        for (int r = 0; r < 4; r++) {
            int i = i0 + w*16 + lg*4 + r;
            int j = j0 + cb*16 + lr;
            float v = acc[cb][r] + (BIAS_ROW ? bias[i] : bias[j]);
            size_t oidx = (size_t)oBatch*bz + (size_t)i*ldo + j;
            if (RES_F32OUT) {
                ((float*)outp)[oidx] = v + resid[(size_t)rBatch*bz + (size_t)i*ldo + j];
            } else {
                ((ushort*)outp)[oidx] = f2bf(v);
            }
        }
    }
}

// ---------------- flash attention: QT=64 (4 waves x 16 rows), KT=64, KV-split
// q,k: [B][N][C] bf16 ; vT: [B][C][N] bf16
// K-tile and V-tile time-share one LDS buffer (static LDS <= 64KB).
#define NSPLIT 4
__global__ __launch_bounds__(256) void flash(
    const ushort* __restrict__ q, const ushort* __restrict__ k, const ushort* __restrict__ vT,
    float* __restrict__ Opart, float2* __restrict__ ml, ushort* __restrict__ aout, int nsplit)
{
    __shared__ ushort skv[256*72];   // K-view: [64][264], V-view: [256][72]
    __shared__ ushort sp[64*72];     // P tile [64][72]
    int b = blockIdx.z, s = blockIdx.y, qt = blockIdx.x;
    int tid = threadIdx.x, w = tid >> 6, lane = tid & 63, lr = lane & 15, lg = lane >> 4;
    int nrow0 = qt*64 + w*16;

    short8 qf[8];
    #pragma unroll
    for (int kc = 0; kc < 8; kc++)
        qf[kc] = *reinterpret_cast<const short8*>(
            q + ((size_t)(b*N_) + nrow0 + lr)*256 + kc*32 + lg*8);

    f32x4 oacc[16] = {};
    float mrow[4] = {-1e30f, -1e30f, -1e30f, -1e30f};
    float lrow[4] = {0.f, 0.f, 0.f, 0.f};

    int tiles_per = 64 / nsplit;
    int t0 = s * tiles_per;
    for (int t = t0; t < t0 + tiles_per; t++) {
        // ---- stage K tile [64][256] into skv (K-view, stride 264)
        #pragma unroll
        for (int it = 0; it < 8; it++) {
            int ch = tid + it*256;          // 0..2047
            int row = ch >> 5, cc = ch & 31;
            *reinterpret_cast<uint4*>(&skv[row*264 + cc*8]) =
                *reinterpret_cast<const uint4*>(k + ((size_t)(b*N_) + t*64 + row)*256 + cc*8);
        }
        __syncthreads();
        // ---- S = Q K^T (per wave: 16 q-rows x 64 m-cols)
        f32x4 sacc[4] = {};
        #pragma unroll
        for (int kc = 0; kc < 8; kc++) {
            #pragma unroll
            for (int cb = 0; cb < 4; cb++) {
                short8 bf = *reinterpret_cast<const short8*>(&skv[(cb*16 + lr)*264 + kc*32 + lg*8]);
                sacc[cb] = __builtin_amdgcn_mfma_f32_16x16x32_bf16(qf[kc], bf, sacc[cb], 0, 0, 0);
            }
        }
        // ---- online softmax (rows = lg*4+r, cols distributed over lr x cb)
        float p[4][4], alpha[4];
        #pragma unroll
        for (int r = 0; r < 4; r++) {
            float mx = fmaxf(fmaxf(sacc[0][r], sacc[1][r]), fmaxf(sacc[2][r], sacc[3][r]));
            mx = fmaxf(mx, __shfl_xor(mx, 1, 64));
            mx = fmaxf(mx, __shfl_xor(mx, 2, 64));
            mx = fmaxf(mx, __shfl_xor(mx, 4, 64));
            mx = fmaxf(mx, __shfl_xor(mx, 8, 64));
            mx *= SCALE_;
            float mnew = fmaxf(mrow[r], mx);
            alpha[r] = __expf(mrow[r] - mnew);
            float ps = 0.f;
            #pragma unroll
            for (int cb = 0; cb < 4; cb++) {
                float pv = __expf(sacc[cb][r]*SCALE_ - mnew);
                p[cb][r] = pv; ps += pv;
            }
            ps += __shfl_xor(ps, 1, 64);
            ps += __shfl_xor(ps, 2, 64);
            ps += __shfl_xor(ps, 4, 64);
            ps += __shfl_xor(ps, 8, 64);
            lrow[r] = lrow[r]*alpha[r] + ps;
            mrow[r] = mnew;
        }
        #pragma unroll
        for (int cb = 0; cb < 16; cb++)
            #pragma unroll
            for (int r = 0; r < 4; r++) oacc[cb][r] *= alpha[r];
        __syncthreads();   // all waves done reading K view
        // ---- stage V tile: vT[b][c][t*64 .. +64] into skv (V-view [256][72]) + write P
        #pragma unroll
        for (int it = 0; it < 8; it++) {
            int ch = tid + it*256;
            int row = ch >> 3, cc = ch & 7;
            *reinterpret_cast<uint4*>(&skv[row*72 + cc*8]) =
                *reinterpret_cast<const uint4*>(vT + ((size_t)(b*C_) + row)*N_ + t*64 + cc*8);
        }
        #pragma unroll
        for (int cb = 0; cb < 4; cb++)
            #pragma unroll
            for (int r = 0; r < 4; r++)
                sp[(w*16 + lg*4 + r)*72 + cb*16 + lr] = f2bf(p[cb][r]);
        __syncthreads();
        // ---- O += P V  (A = P from sp, B = V via vT rows in skv V-view)
        #pragma unroll
        for (int kc = 0; kc < 2; kc++) {
            short8 af = *reinterpret_cast<const short8*>(&sp[(w*16 + lr)*72 + kc*32 + lg*8]);
            #pragma unroll
            for (int cb = 0; cb < 16; cb++) {
                short8 bf = *reinterpret_cast<const short8*>(&skv[(cb*16 + lr)*72 + kc*32 + lg*8]);
                oacc[cb] = __builtin_amdgcn_mfma_f32_16x16x32_bf16(af, bf, oacc[cb], 0, 0, 0);
            }
        }
        __syncthreads();   // done reading V/P before next K stage
    }
    if (nsplit == 1) {
        #pragma unroll
        for (int r = 0; r < 4; r++) {
            float inv = 1.f / lrow[r];
            int n = nrow0 + lg*4 + r;
            #pragma unroll
            for (int cb = 0; cb < 16; cb++)
                aout[((size_t)(b*N_) + n)*256 + cb*16 + lr] = f2bf(oacc[cb][r]*inv);
        }
    } else {
        size_t base = ((size_t)(b*nsplit + s))*N_;
        #pragma unroll
        for (int r = 0; r < 4; r++) {
            int n = nrow0 + lg*4 + r;
            #pragma unroll
            for (int cb = 0; cb < 16; cb++)
                Opart[(base + n)*256 + cb*16 + lr] = oacc[cb][r];
            if (lr == 0) ml[base + n] = make_float2(mrow[r], lrow[r]);
        }
    }
}

// ---------------- combine NSPLIT partial softmax results -> a[b][n][c] bf16
__global__ void combine(const float* __restrict__ Opart, const float2* __restrict__ ml,
                        ushort* __restrict__ aout) {
    int g = threadIdx.x >> 6, lane = threadIdx.x & 63;
    int idx = blockIdx.x*4 + g;           // b*N + n
    int b = idx >> 12, n = idx & 4095;
    float2 mls[NSPLIT];
    float M = -1e30f;
    #pragma unroll
    for (int s = 0; s < NSPLIT; s++) {
        mls[s] = ml[((size_t)(b*NSPLIT + s))*N_ + n];
        M = fmaxf(M, mls[s].x);
    }
    float L = 0.f, wgt[NSPLIT];
    #pragma unroll
    for (int s = 0; s < NSPLIT; s++) { wgt[s] = __expf(mls[s].x - M); L += mls[s].y * wgt[s]; }
    float4 acc = make_float4(0.f, 0.f, 0.f, 0.f);
    #pragma unroll
    for (int s = 0; s < NSPLIT; s++) {
        float4 o = *reinterpret_cast<const float4*>(
            Opart + (((size_t)(b*NSPLIT + s))*N_ + n)*256 + lane*4);
        acc.x += wgt[s]*o.x; acc.y += wgt[s]*o.y; acc.z += wgt[s]*o.z; acc.w += wgt[s]*o.w;
    }
    float inv = 1.f / L;
    ushort4 r; r.x = f2bf(acc.x*inv); r.y = f2bf(acc.y*inv); r.z = f2bf(acc.z*inv); r.w = f2bf(acc.w*inv);
    *reinterpret_cast<ushort4*>(aout + ((size_t)idx)*256 + lane*4) = r;
}

extern "C" void kernel_launch(void* const* d_in, const int* in_sizes, int n_in,
                              void* d_out, int out_size, void* d_ws, size_t ws_size,
                              hipStream_t stream) {
    const float* x     = (const float*)d_in[0];
    const float* gamma = (const float*)d_in[1];
    const float* beta  = (const float*)d_in[2];
    const float* Wq = (const float*)d_in[3]; const float* bq = (const float*)d_in[4];
    const float* Wk = (const float*)d_in[5]; const float* bk = (const float*)d_in[6];
    const float* Wv = (const float*)d_in[7]; const float* bv = (const float*)d_in[8];
    const float* Wp = (const float*)d_in[9]; const float* bp = (const float*)d_in[10];
    float* out = (float*)d_out;

    char* ws = (char*)d_ws;
    float2* stats = (float2*)ws;                       // 512 B
    ushort* wqb = (ushort*)(ws + 1024);                // 4 x 128 KB
    ushort* wkb = wqb + 65536;
    ushort* wvb = wkb + 65536;
    ushort* wpb = wvb + 65536;
    ushort* ht  = (ushort*)(ws + 1024 + 524288);       // 5 x 4 MB bf16 buffers
    const size_t NB = (size_t)B_ * N_ * C_;
    ushort* qb  = ht  + NB;
    ushort* kb  = qb  + NB;
    ushort* vTb = kb  + NB;
    ushort* ab  = vTb + NB;
    char* after = (char*)(ab + NB);
    float2* mlp  = (float2*)after;                     // 256 KB
    float* Opart = (float*)(after + 262144);           // 32 MB

    int nsplit = (ws_size >= (size_t)56*1024*1024) ? NSPLIT : 1;

    gn_stats<<<64, 256, 0, stream>>>(x, stats);
    wconv<<<256, 256, 0, stream>>>(Wq, Wk, Wv, Wp, wqb);
    gnorm_t<<<dim3(128, 8, 2), dim3(32, 8), 0, stream>>>(x, stats, gamma, beta, ht);
    // q[n][o], k[n][o]
    gemm_nt<false,false><<<dim3(64,4,2), 256, 0, stream>>>(ht, wqb, bq, nullptr, qb,
        (long)N_*C_, 0, (long)N_*C_, 0, 256);
    gemm_nt<false,false><<<dim3(64,4,2), 256, 0, stream>>>(ht, wkb, bk, nullptr, kb,
        (long)N_*C_, 0, (long)N_*C_, 0, 256);
    // vT[o][n]
    gemm_nt<true,false><<<dim3(4,64,2), 256, 0, stream>>>(wvb, ht, bv, nullptr, vTb,
        0, (long)N_*C_, (long)C_*N_, 0, N_);
    flash<<<dim3(64, nsplit, 2), 256, 0, stream>>>(qb, kb, vTb, Opart, mlp, ab, nsplit);
    if (nsplit > 1) combine<<<2048, 256, 0, stream>>>(Opart, mlp, ab);
    // y[o][n] = x + bp[o] + Wp·a
    gemm_nt<true,true><<<dim3(4,64,2), 256, 0, stream>>>(wpb, ab, bp, x, out,
        0, (long)N_*C_, (long)C_*N_, (long)C_*N_, N_);
}